// Round 3
// baseline (657.372 us; speedup 1.0000x reference)
//
#include <hip/hip_runtime.h>

// Normalized correlation layer, MI355X.  B=8 H=W=32 C=64 K=5 PAD=2.
// out[b,r,w, c*160 + e*32 + f] = sum_p P1n[b,r,w,c,p] * P2n[b,r+e,f,c,p]
// Identity: sum (a-m1)(b-m2) = sum a*b - 25*m1*m2, scaled by (1/s1)(1/s2).
// R3 changes vs R2: __launch_bounds__(256,4) to force <=128 VGPR (4 blk/CU),
// rolling x2-row register window in main loop (125 -> 45 ds_read_b32/thread,
// statically indexed; r>=30 remap rows take the generic fallback path),
// float2 staging (channel pair adjacent in memory).

namespace {

constexpr int OUTC = 64 * 5 * 32; // 10240

__global__ __launch_bounds__(256, 4)
void ncc_kernel(const float* __restrict__ in1, const float* __restrict__ in2,
                float* __restrict__ out) {
    // block = (b, r, cpair); c0 = cpair*2
    const int bid = blockIdx.x;
    const int cpair = bid & 31;
    const int r = (bid >> 5) & 31;
    const int b = bid >> 10;
    const int c0 = cpair * 2;

    __shared__ __align__(16) float x1s[2][5][36];  // rows r..r+4 of x1pad
    __shared__ __align__(16) float x2s[2][9][36];  // rows r..r+8 of x2pad
    __shared__ float m1s[2][32], i1s[2][32];       // P1 stats per w
    __shared__ float m2s[2][5][32], i2s[2][5][32]; // P2 stats per (e,f)

    const int tid = threadIdx.x;

    // ---- stage x1pad rows r..r+4 (both channels at once via float2) ----
    if (tid < 180) {
        const int i = tid / 36;
        const int pc = tid - i * 36;
        const int ir = r + i - 2;
        const int ic = pc - 2;
        float2 v = make_float2(0.f, 0.f);
        if (ir >= 0 && ir < 32 && ic >= 0 && ic < 32)
            v = *reinterpret_cast<const float2*>(&in1[((b * 32 + ir) * 32 + ic) * 64 + c0]);
        x1s[0][i][pc] = v.x;
        x1s[1][i][pc] = v.y;
    }
    // ---- stage x2pad rows r..r+8 ----
    for (int idx = tid; idx < 324; idx += 256) {
        const int k = idx / 36;
        const int pc = idx - k * 36;
        const int ir = r + k - 4;
        const int ic = pc - 2;
        float2 v = make_float2(0.f, 0.f);
        if (ir >= 0 && ir < 32 && ic >= 0 && ic < 32)
            v = *reinterpret_cast<const float2*>(&in2[((b * 32 + ir) * 32 + ic) * 64 + c0]);
        x2s[0][k][pc] = v.x;
        x2s[1][k][pc] = v.y;
    }
    __syncthreads();

    // ---- P1 patch stats per (c2, w) ----
    if (tid < 64) {
        const int c2 = tid >> 5, w = tid & 31;
        float s = 0.f, ss = 0.f;
        #pragma unroll
        for (int i = 0; i < 5; ++i)
            #pragma unroll
            for (int j = 0; j < 5; ++j) {
                const float v = x1s[c2][i][w + j];
                s += v; ss += v * v;
            }
        const float m = s * (1.0f / 25.0f);
        const float var = ss * (1.0f / 25.0f) - m * m;
        m1s[c2][w] = m;
        i1s[c2][w] = 1.0f / sqrtf(fmaxf(var, 1e-30f));
    }
    // ---- P2 patch stats per (c2, e, f); row remap lr<=33?lr:lr-2 ----
    for (int t = tid; t < 320; t += 256) {
        const int c2 = t / 160;
        const int rem = t - c2 * 160;
        const int e = rem >> 5;
        const int f = rem & 31;
        const int bb = (r + e <= 33) ? e : e - 2;
        float s = 0.f, ss = 0.f;
        #pragma unroll
        for (int i = 0; i < 5; ++i)
            #pragma unroll
            for (int j = 0; j < 5; ++j) {
                const float v = x2s[c2][bb + i][f + j];
                s += v; ss += v * v;
            }
        const float m = s * (1.0f / 25.0f);
        const float var = ss * (1.0f / 25.0f) - m * m;
        m2s[c2][e][f] = m;
        i2s[c2][e][f] = 1.0f / sqrtf(fmaxf(var, 1e-30f));
    }
    __syncthreads();

    // ---- main correlation: lane = (c2, f), wave owns 8 w values ----
    const int lane = tid & 63;
    const int wave = tid >> 6;
    const int c2 = lane >> 5;
    const int f = lane & 31;
    const int wbase = wave * 8;

    float acc[8][5];
    #pragma unroll
    for (int wi = 0; wi < 8; ++wi)
        #pragma unroll
        for (int e = 0; e < 5; ++e) acc[wi][e] = 0.f;

    if (r < 30) {
        // FAST PATH: base_e[e] == e. Rolling 5-row register window, rows i..i+4.
        // All window indices compile-time ((i+e)%5 under full unroll).
        float win[5][5];
        #pragma unroll
        for (int k = 0; k < 5; ++k) {
            const float* bp = &x2s[c2][k][f];
            #pragma unroll
            for (int j = 0; j < 5; ++j) win[k][j] = bp[j];
        }
        #pragma unroll
        for (int i = 0; i < 5; ++i) {
            float A[12];
            const float4* ap = reinterpret_cast<const float4*>(&x1s[c2][i][wbase]);
            const float4 a0 = ap[0], a1 = ap[1], a2 = ap[2];
            A[0] = a0.x; A[1] = a0.y; A[2]  = a0.z; A[3]  = a0.w;
            A[4] = a1.x; A[5] = a1.y; A[6]  = a1.z; A[7]  = a1.w;
            A[8] = a2.x; A[9] = a2.y; A[10] = a2.z; A[11] = a2.w;

            #pragma unroll
            for (int j = 0; j < 5; ++j)
                #pragma unroll
                for (int e = 0; e < 5; ++e) {
                    const float bv = win[(i + e) % 5][j];
                    #pragma unroll
                    for (int wi = 0; wi < 8; ++wi)
                        acc[wi][e] += A[wi + j] * bv;
                }
            if (i < 4) {
                // row i+5 replaces row i (slot i%5)
                const float* bp = &x2s[c2][i + 5][f];
                #pragma unroll
                for (int j = 0; j < 5; ++j) win[i % 5][j] = bp[j];
            }
        }
    } else {
        // SLOW PATH (r = 30, 31): remapped rows, generic LDS reads.
        int base_e[5];
        #pragma unroll
        for (int e = 0; e < 5; ++e) base_e[e] = (r + e <= 33) ? e : e - 2;

        #pragma unroll
        for (int i = 0; i < 5; ++i) {
            float A[12];
            const float4* ap = reinterpret_cast<const float4*>(&x1s[c2][i][wbase]);
            const float4 a0 = ap[0], a1 = ap[1], a2 = ap[2];
            A[0] = a0.x; A[1] = a0.y; A[2]  = a0.z; A[3]  = a0.w;
            A[4] = a1.x; A[5] = a1.y; A[6]  = a1.z; A[7]  = a1.w;
            A[8] = a2.x; A[9] = a2.y; A[10] = a2.z; A[11] = a2.w;

            float Br[5][5];
            #pragma unroll
            for (int e = 0; e < 5; ++e) {
                const float* bp = &x2s[c2][base_e[e] + i][f];
                #pragma unroll
                for (int j = 0; j < 5; ++j) Br[e][j] = bp[j];
            }
            #pragma unroll
            for (int j = 0; j < 5; ++j)
                #pragma unroll
                for (int e = 0; e < 5; ++e)
                    #pragma unroll
                    for (int wi = 0; wi < 8; ++wi)
                        acc[wi][e] += A[wi + j] * Br[e][j];
        }
    }

    // ---- epilogue: normalization correction + coalesced stores ----
    float m2v[5], i2v[5];
    #pragma unroll
    for (int e = 0; e < 5; ++e) { m2v[e] = m2s[c2][e][f]; i2v[e] = i2s[c2][e][f]; }

    const int outrow = (b * 32 + r) * 32;
    float* op0 = out + (size_t)outrow * OUTC + (c0 + c2) * 160 + f;
    #pragma unroll
    for (int wi = 0; wi < 8; ++wi) {
        const int w = wbase + wi;
        const float m1 = m1s[c2][w];
        const float i1 = i1s[c2][w];
        float* op = op0 + (size_t)w * OUTC;
        #pragma unroll
        for (int e = 0; e < 5; ++e) {
            op[e * 32] = (acc[wi][e] - 25.0f * m1 * m2v[e]) * (i1 * i2v[e]);
        }
    }
}

} // namespace

extern "C" void kernel_launch(void* const* d_in, const int* in_sizes, int n_in,
                              void* d_out, int out_size, void* d_ws, size_t ws_size,
                              hipStream_t stream) {
    const float* in1 = (const float*)d_in[0];
    const float* in2 = (const float*)d_in[1];
    float* out = (float*)d_out;
    // grid = B(8) * r(32) * cpair(32) = 8192 blocks
    hipLaunchKernelGGL(ncc_kernel, dim3(8192), dim3(256), 0, stream, in1, in2, out);
}

// Round 9
// 382.365 us; speedup vs baseline: 1.7192x; 1.7192x over previous
//
#include <hip/hip_runtime.h>

// Normalized correlation layer, MI355X.  B=8 H=W=32 C=64 K=5 PAD=2.
// out[b,r,w, c*160 + e*32 + f] = sum_p P1n[b,r,w,c,p] * P2n[b,r+e,f,c,p]
// Identity: sum (a-m1)(b-m2) = sum a*b - 25*m1*m2, scaled by (1/s1)(1/s2).
// R4 vs R3: removed __launch_bounds__ min-waves cap — R3's (256,4) clamped
// the allocator to 64 VGPR and spilled acc/win to scratch (FETCH 623MB,
// WRITE 1.45GB vs 17/328MB analytic => 2.5x regression). Keep rolling
// x2-row register window (45 ds_read_b32/thread vs 125) + float2 staging.

namespace {

constexpr int OUTC = 64 * 5 * 32; // 10240

__global__ __launch_bounds__(256)
void ncc_kernel(const float* __restrict__ in1, const float* __restrict__ in2,
                float* __restrict__ out) {
    // block = (b, r, cpair); c0 = cpair*2
    const int bid = blockIdx.x;
    const int cpair = bid & 31;
    const int r = (bid >> 5) & 31;
    const int b = bid >> 10;
    const int c0 = cpair * 2;

    __shared__ __align__(16) float x1s[2][5][36];  // rows r..r+4 of x1pad
    __shared__ __align__(16) float x2s[2][9][36];  // rows r..r+8 of x2pad
    __shared__ float m1s[2][32], i1s[2][32];       // P1 stats per w
    __shared__ float m2s[2][5][32], i2s[2][5][32]; // P2 stats per (e,f)

    const int tid = threadIdx.x;

    // ---- stage x1pad rows r..r+4 (both channels at once via float2) ----
    if (tid < 180) {
        const int i = tid / 36;
        const int pc = tid - i * 36;
        const int ir = r + i - 2;
        const int ic = pc - 2;
        float2 v = make_float2(0.f, 0.f);
        if (ir >= 0 && ir < 32 && ic >= 0 && ic < 32)
            v = *reinterpret_cast<const float2*>(&in1[((b * 32 + ir) * 32 + ic) * 64 + c0]);
        x1s[0][i][pc] = v.x;
        x1s[1][i][pc] = v.y;
    }
    // ---- stage x2pad rows r..r+8 ----
    for (int idx = tid; idx < 324; idx += 256) {
        const int k = idx / 36;
        const int pc = idx - k * 36;
        const int ir = r + k - 4;
        const int ic = pc - 2;
        float2 v = make_float2(0.f, 0.f);
        if (ir >= 0 && ir < 32 && ic >= 0 && ic < 32)
            v = *reinterpret_cast<const float2*>(&in2[((b * 32 + ir) * 32 + ic) * 64 + c0]);
        x2s[0][k][pc] = v.x;
        x2s[1][k][pc] = v.y;
    }
    __syncthreads();

    // ---- P1 patch stats per (c2, w) ----
    if (tid < 64) {
        const int c2 = tid >> 5, w = tid & 31;
        float s = 0.f, ss = 0.f;
        #pragma unroll
        for (int i = 0; i < 5; ++i)
            #pragma unroll
            for (int j = 0; j < 5; ++j) {
                const float v = x1s[c2][i][w + j];
                s += v; ss += v * v;
            }
        const float m = s * (1.0f / 25.0f);
        const float var = ss * (1.0f / 25.0f) - m * m;
        m1s[c2][w] = m;
        i1s[c2][w] = 1.0f / sqrtf(fmaxf(var, 1e-30f));
    }
    // ---- P2 patch stats per (c2, e, f); row remap lr<=33?lr:lr-2 ----
    for (int t = tid; t < 320; t += 256) {
        const int c2 = t / 160;
        const int rem = t - c2 * 160;
        const int e = rem >> 5;
        const int f = rem & 31;
        const int bb = (r + e <= 33) ? e : e - 2;
        float s = 0.f, ss = 0.f;
        #pragma unroll
        for (int i = 0; i < 5; ++i)
            #pragma unroll
            for (int j = 0; j < 5; ++j) {
                const float v = x2s[c2][bb + i][f + j];
                s += v; ss += v * v;
            }
        const float m = s * (1.0f / 25.0f);
        const float var = ss * (1.0f / 25.0f) - m * m;
        m2s[c2][e][f] = m;
        i2s[c2][e][f] = 1.0f / sqrtf(fmaxf(var, 1e-30f));
    }
    __syncthreads();

    // ---- main correlation: lane = (c2, f), wave owns 8 w values ----
    const int lane = tid & 63;
    const int wave = tid >> 6;
    const int c2 = lane >> 5;
    const int f = lane & 31;
    const int wbase = wave * 8;

    float acc[8][5];
    #pragma unroll
    for (int wi = 0; wi < 8; ++wi)
        #pragma unroll
        for (int e = 0; e < 5; ++e) acc[wi][e] = 0.f;

    if (r < 30) {
        // FAST PATH: base_e[e] == e. Rolling 5-row register window, rows i..i+4.
        // All window indices compile-time ((i+e)%5 under full unroll).
        float win[5][5];
        #pragma unroll
        for (int k = 0; k < 5; ++k) {
            const float* bp = &x2s[c2][k][f];
            #pragma unroll
            for (int j = 0; j < 5; ++j) win[k][j] = bp[j];
        }
        #pragma unroll
        for (int i = 0; i < 5; ++i) {
            float A[12];
            const float4* ap = reinterpret_cast<const float4*>(&x1s[c2][i][wbase]);
            const float4 a0 = ap[0], a1 = ap[1], a2 = ap[2];
            A[0] = a0.x; A[1] = a0.y; A[2]  = a0.z; A[3]  = a0.w;
            A[4] = a1.x; A[5] = a1.y; A[6]  = a1.z; A[7]  = a1.w;
            A[8] = a2.x; A[9] = a2.y; A[10] = a2.z; A[11] = a2.w;

            #pragma unroll
            for (int j = 0; j < 5; ++j)
                #pragma unroll
                for (int e = 0; e < 5; ++e) {
                    const float bv = win[(i + e) % 5][j];
                    #pragma unroll
                    for (int wi = 0; wi < 8; ++wi)
                        acc[wi][e] += A[wi + j] * bv;
                }
            if (i < 4) {
                // row i+5 replaces row i (slot i%5)
                const float* bp = &x2s[c2][i + 5][f];
                #pragma unroll
                for (int j = 0; j < 5; ++j) win[i % 5][j] = bp[j];
            }
        }
    } else {
        // SLOW PATH (r = 30, 31): remapped rows, generic LDS reads.
        int base_e[5];
        #pragma unroll
        for (int e = 0; e < 5; ++e) base_e[e] = (r + e <= 33) ? e : e - 2;

        #pragma unroll
        for (int i = 0; i < 5; ++i) {
            float A[12];
            const float4* ap = reinterpret_cast<const float4*>(&x1s[c2][i][wbase]);
            const float4 a0 = ap[0], a1 = ap[1], a2 = ap[2];
            A[0] = a0.x; A[1] = a0.y; A[2]  = a0.z; A[3]  = a0.w;
            A[4] = a1.x; A[5] = a1.y; A[6]  = a1.z; A[7]  = a1.w;
            A[8] = a2.x; A[9] = a2.y; A[10] = a2.z; A[11] = a2.w;

            float Br[5][5];
            #pragma unroll
            for (int e = 0; e < 5; ++e) {
                const float* bp = &x2s[c2][base_e[e] + i][f];
                #pragma unroll
                for (int j = 0; j < 5; ++j) Br[e][j] = bp[j];
            }
            #pragma unroll
            for (int j = 0; j < 5; ++j)
                #pragma unroll
                for (int e = 0; e < 5; ++e)
                    #pragma unroll
                    for (int wi = 0; wi < 8; ++wi)
                        acc[wi][e] += A[wi + j] * Br[e][j];
        }
    }

    // ---- epilogue: normalization correction + coalesced stores ----
    float m2v[5], i2v[5];
    #pragma unroll
    for (int e = 0; e < 5; ++e) { m2v[e] = m2s[c2][e][f]; i2v[e] = i2s[c2][e][f]; }

    const int outrow = (b * 32 + r) * 32;
    float* op0 = out + (size_t)outrow * OUTC + (c0 + c2) * 160 + f;
    #pragma unroll
    for (int wi = 0; wi < 8; ++wi) {
        const int w = wbase + wi;
        const float m1 = m1s[c2][w];
        const float i1 = i1s[c2][w];
        float* op = op0 + (size_t)w * OUTC;
        #pragma unroll
        for (int e = 0; e < 5; ++e) {
            op[e * 32] = (acc[wi][e] - 25.0f * m1 * m2v[e]) * (i1 * i2v[e]);
        }
    }
}

} // namespace

extern "C" void kernel_launch(void* const* d_in, const int* in_sizes, int n_in,
                              void* d_out, int out_size, void* d_ws, size_t ws_size,
                              hipStream_t stream) {
    const float* in1 = (const float*)d_in[0];
    const float* in2 = (const float*)d_in[1];
    float* out = (float*)d_out;
    // grid = B(8) * r(32) * cpair(32) = 8192 blocks
    hipLaunchKernelGGL(ncc_kernel, dim3(8192), dim3(256), 0, stream, in1, in2, out);
}

// Round 10
// 355.355 us; speedup vs baseline: 1.8499x; 1.0760x over previous
//
#include <hip/hip_runtime.h>

// Normalized correlation layer, MI355X.  B=8 H=W=32 C=64 K=5 PAD=2.
// out[b,r,w, c*160 + e*32 + f] = sum_p P1n[b,r,w,c,p] * P2n[b,r+e,f,c,p]
// Identity: sum (a-m1)(b-m2) = sum a*b - 25*m1*m2, scaled by (1/s1)(1/s2).
// R5 redesign vs R4 (R2~R4 at ~165us kernel regardless of inner loop =>
// latency/store-pattern bound, not VALU/LDS): block = (b, r, 8 channels),
// 2048 blocks (8 rounds/CU instead of 32). Each thread owns (ch, f) and
// computes ALL 32 w: the x2 window win9[9][5] is w-invariant -> loaded to
// registers ONCE per thread. Stores per w are 5KB-contiguous per block
// (vs 640B chunks), issued in 8 bursts spread over the block's lifetime.

namespace {

constexpr int OUTC = 64 * 5 * 32; // 10240

// Row-remap bases B0..B4 are compile-time so win9 indexing stays in regs.
template<int B0, int B1, int B2, int B3, int B4>
__device__ __forceinline__ void compute_and_store(
    const float (&win9)[9][5], const float* x1row,   // x1s[ch] base, row stride 36
    const float* m1p, const float* i1p,              // m1s[ch], i1s[ch]
    const float (&m2v)[5], const float (&i2v)[5],
    float* opf)                                      // out + row*OUTC + chan*160 + f
{
    #pragma unroll 1
    for (int wg = 0; wg < 8; ++wg) {
        const int wbase = wg * 4;
        float acc[4][5];
        #pragma unroll
        for (int wi = 0; wi < 4; ++wi)
            #pragma unroll
            for (int e = 0; e < 5; ++e) acc[wi][e] = 0.f;

        #pragma unroll
        for (int i = 0; i < 5; ++i) {
            const float4 a0 = *reinterpret_cast<const float4*>(&x1row[i * 36 + wbase]);
            const float4 a1 = *reinterpret_cast<const float4*>(&x1row[i * 36 + wbase + 4]);
            const float A[8] = {a0.x, a0.y, a0.z, a0.w, a1.x, a1.y, a1.z, a1.w};
            #pragma unroll
            for (int j = 0; j < 5; ++j) {
                #pragma unroll
                for (int wi = 0; wi < 4; ++wi) {
                    const float a = A[wi + j];
                    acc[wi][0] += a * win9[B0 + i][j];
                    acc[wi][1] += a * win9[B1 + i][j];
                    acc[wi][2] += a * win9[B2 + i][j];
                    acc[wi][3] += a * win9[B3 + i][j];
                    acc[wi][4] += a * win9[B4 + i][j];
                }
            }
        }
        #pragma unroll
        for (int wi = 0; wi < 4; ++wi) {
            const int w = wbase + wi;
            const float m1 = m1p[w];
            const float i1 = i1p[w];
            float* op = opf + (size_t)w * OUTC;
            #pragma unroll
            for (int e = 0; e < 5; ++e)
                op[e * 32] = (acc[wi][e] - 25.0f * m1 * m2v[e]) * (i1 * i2v[e]);
        }
    }
}

__global__ __launch_bounds__(256)
void ncc_kernel(const float* __restrict__ in1, const float* __restrict__ in2,
                float* __restrict__ out) {
    // block = (b, r, c8): 8 channels per block; grid = 8*32*8 = 2048
    const int bid = blockIdx.x;
    const int c8 = bid & 7;
    const int r  = (bid >> 3) & 31;
    const int b  = bid >> 8;
    const int c0 = c8 * 8;

    __shared__ __align__(16) float x1s[8][5][36];   //  5.8 KB
    __shared__ __align__(16) float x2s[8][9][36];   // 10.4 KB
    __shared__ float m1s[8][32], i1s[8][32];        //  2.0 KB
    __shared__ float m2s[8][5][32], i2s[8][5][32];  // 10.2 KB  (total 28.4 KB)

    const int tid = threadIdx.x;

    // ---- stage x1pad rows r..r+4 (float4 = 4 channels per load) ----
    for (int t = tid; t < 360; t += 256) {
        const int cg = t / 180;            // channel group (4 ch)
        const int rem = t - cg * 180;
        const int i = rem / 36;
        const int pc = rem - i * 36;
        const int ir = r + i - 2;
        const int ic = pc - 2;
        float4 v = make_float4(0.f, 0.f, 0.f, 0.f);
        if (ir >= 0 && ir < 32 && ic >= 0 && ic < 32)
            v = *reinterpret_cast<const float4*>(&in1[((b * 32 + ir) * 32 + ic) * 64 + c0 + cg * 4]);
        x1s[cg * 4 + 0][i][pc] = v.x;
        x1s[cg * 4 + 1][i][pc] = v.y;
        x1s[cg * 4 + 2][i][pc] = v.z;
        x1s[cg * 4 + 3][i][pc] = v.w;
    }
    // ---- stage x2pad rows r..r+8 ----
    for (int t = tid; t < 648; t += 256) {
        const int cg = t / 324;
        const int rem = t - cg * 324;
        const int k = rem / 36;
        const int pc = rem - k * 36;
        const int ir = r + k - 4;
        const int ic = pc - 2;
        float4 v = make_float4(0.f, 0.f, 0.f, 0.f);
        if (ir >= 0 && ir < 32 && ic >= 0 && ic < 32)
            v = *reinterpret_cast<const float4*>(&in2[((b * 32 + ir) * 32 + ic) * 64 + c0 + cg * 4]);
        x2s[cg * 4 + 0][k][pc] = v.x;
        x2s[cg * 4 + 1][k][pc] = v.y;
        x2s[cg * 4 + 2][k][pc] = v.z;
        x2s[cg * 4 + 3][k][pc] = v.w;
    }
    __syncthreads();

    // ---- P1 patch stats: 8ch x 32w = 256 entries, one per thread ----
    {
        const int ch = tid >> 5, w = tid & 31;
        float s = 0.f, ss = 0.f;
        #pragma unroll
        for (int i = 0; i < 5; ++i)
            #pragma unroll
            for (int j = 0; j < 5; ++j) {
                const float v = x1s[ch][i][w + j];
                s += v; ss += v * v;
            }
        const float m = s * (1.0f / 25.0f);
        const float var = ss * (1.0f / 25.0f) - m * m;
        m1s[ch][w] = m;
        i1s[ch][w] = 1.0f / sqrtf(fmaxf(var, 1e-30f));
    }
    // ---- P2 patch stats: 8ch x 5e x 32f = 1280 entries (5 per thread) ----
    for (int t = tid; t < 1280; t += 256) {
        const int ch = t / 160;
        const int rem = t - ch * 160;
        const int e = rem >> 5;
        const int f = rem & 31;
        const int bb = (r + e <= 33) ? e : e - 2;   // list-row remap
        float s = 0.f, ss = 0.f;
        #pragma unroll
        for (int i = 0; i < 5; ++i)
            #pragma unroll
            for (int j = 0; j < 5; ++j) {
                const float v = x2s[ch][bb + i][f + j];
                s += v; ss += v * v;
            }
        const float m = s * (1.0f / 25.0f);
        const float var = ss * (1.0f / 25.0f) - m * m;
        m2s[ch][e][f] = m;
        i2s[ch][e][f] = 1.0f / sqrtf(fmaxf(var, 1e-30f));
    }
    __syncthreads();

    // ---- main: wave = local cpair; thread owns (ch, f) for ALL 32 w ----
    const int lane = tid & 63;
    const int wave = tid >> 6;
    const int c2 = lane >> 5;
    const int f = lane & 31;
    const int ch = wave * 2 + c2;

    // w-invariant x2 window: 9 rows x 5 cols into registers, once.
    float win9[9][5];
    #pragma unroll
    for (int k = 0; k < 9; ++k) {
        const float* bp = &x2s[ch][k][f];
        #pragma unroll
        for (int j = 0; j < 5; ++j) win9[k][j] = bp[j];
    }
    float m2v[5], i2v[5];
    #pragma unroll
    for (int e = 0; e < 5; ++e) { m2v[e] = m2s[ch][e][f]; i2v[e] = i2s[ch][e][f]; }

    float* opf = out + (size_t)((b * 32 + r) * 32) * OUTC + (c0 + ch) * 160 + f;
    const float* x1row = &x1s[ch][0][0];
    const float* m1p = m1s[ch];
    const float* i1p = i1s[ch];

    if (r < 30)        compute_and_store<0, 1, 2, 3, 4>(win9, x1row, m1p, i1p, m2v, i2v, opf);
    else if (r == 30)  compute_and_store<0, 1, 2, 3, 2>(win9, x1row, m1p, i1p, m2v, i2v, opf);
    else               compute_and_store<0, 1, 2, 1, 2>(win9, x1row, m1p, i1p, m2v, i2v, opf);
}

} // namespace

extern "C" void kernel_launch(void* const* d_in, const int* in_sizes, int n_in,
                              void* d_out, int out_size, void* d_ws, size_t ws_size,
                              hipStream_t stream) {
    const float* in1 = (const float*)d_in[0];
    const float* in2 = (const float*)d_in[1];
    float* out = (float*)d_out;
    // grid = B(8) * r(32) * c8(8) = 2048 blocks
    hipLaunchKernelGGL(ncc_kernel, dim3(2048), dim3(256), 0, stream, in1, in2, out);
}